// Round 3
// baseline (306.828 us; speedup 1.0000x reference)
//
#include <hip/hip_runtime.h>
#include <hip/hip_bf16.h>

#define NB 4
#define NH 32
#define NHKV 8
#define NG 4
#define ND 128
#define NP 128
#define NS 64
#define KK 15
#define KP 16
#define NEGF -1000000000.0f
#define SM_SCALE 0.088388347648318447f

// workspace layout (float offsets)
#define WS_QH   0                                  // B*H*D          = 16384
#define WS_KR   16384                              // B*Hkv*D        = 4096
#define WS_CUR  20480                              // B*H            = 512
#define WS_SC   20992                              // B*Hkv*G*P*S    = 1048576
#define WS_ST   (WS_SC + NB*NHKV*NG*NP*NS)         // B*Hkv*G*P      = 16384
#define WS_SEL  (WS_ST + NB*NHKV*NG*NP)            // B*Hkv*G*KP     = 2048 (int)
#define WS_PW   (WS_SEL + NB*NHKV*NG*KP)           // B*Hkv*G*1024   = 131072
// total ~4.9 MB

__global__ __launch_bounds__(256) void prep_kernel(const float* __restrict__ q,
                                                   const float* __restrict__ k,
                                                   const int* __restrict__ tstep,
                                                   float* __restrict__ ws) {
    float* QH = ws + WS_QH;
    float* KR = ws + WS_KR;
    float* CUR = ws + WS_CUR;
    const float pos = (float)(tstep[0] - 1);
    const int tid = threadIdx.x;
    // RoPE q: 128 heads x 64 pairs
    for (int i = tid; i < NB * NH * 64; i += 256) {
        int j = i & 63, head = i >> 6;
        float invf = 1.0f / powf(10000.0f, (float)j * (1.0f / 64.0f));
        float sng, csn;
        sincosf(pos * invf, &sng, &csn);
        float x1 = q[head * ND + j], x2 = q[head * ND + 64 + j];
        QH[head * ND + j] = x1 * csn - x2 * sng;
        QH[head * ND + 64 + j] = x1 * sng + x2 * csn;
    }
    // RoPE k: 32 heads x 64 pairs
    for (int i = tid; i < NB * NHKV * 64; i += 256) {
        int j = i & 63, head = i >> 6;
        float invf = 1.0f / powf(10000.0f, (float)j * (1.0f / 64.0f));
        float sng, csn;
        sincosf(pos * invf, &sng, &csn);
        float x1 = k[head * ND + j], x2 = k[head * ND + 64 + j];
        KR[head * ND + j] = x1 * csn - x2 * sng;
        KR[head * ND + 64 + j] = x1 * sng + x2 * csn;
    }
    __syncthreads();
    // current-token scores: 128 dots of length 128
    for (int h = tid; h < NB * NH; h += 256) {
        int b = h >> 5, hh = h & 31, hkv = hh >> 2;
        const float* qr = QH + h * ND;
        const float* kr = KR + (b * NHKV + hkv) * ND;
        float acc = 0.f;
#pragma unroll 8
        for (int d = 0; d < ND; ++d) acc += qr[d] * kr[d];
        CUR[h] = acc * SM_SCALE;
    }
}

// one block per (b, hkv, page); wave w computes query head g=w for all 64 s
__global__ __launch_bounds__(256) void score_kernel(const int* __restrict__ kc,
                                                    const float* __restrict__ kvs,
                                                    const int* __restrict__ lens,
                                                    float* __restrict__ ws) {
    __shared__ float klds[NS][132];   // pad to 132 floats: bank-uniform b128 reads
    __shared__ float qlds[NG][ND];
    const float* QH = ws + WS_QH;
    float* SC = ws + WS_SC;
    float* ST = ws + WS_ST;
    const int blk = blockIdx.x;
    const int p = blk & (NP - 1);
    const int bh = blk >> 7;
    const int hkv = bh & (NHKV - 1);
    const int b = bh >> 3;
    const int len = max(lens[b], 1);
    const int tid = threadIdx.x;
    const int g = tid >> 6, s = tid & 63;
    const int bhg = (b * NHKV + hkv) * NG + g;
    if (p * NS >= len) {  // fully masked page: skip K load
        SC[bhg * (NP * NS) + p * NS + s] = NEGF;
        if (s == 0) ST[bhg * NP + p] = NEGF;
        return;
    }
    for (int i = tid; i < NG * ND; i += 256)
        qlds[i >> 7][i & 127] = QH[(b * NH + hkv * NG + (i >> 7)) * ND + (i & 127)];
    const int4* src = (const int4*)(kc + ((b * NP + p) * NS * NHKV + hkv) * ND);
    for (int i = tid; i < NS * 32; i += 256) {
        int ss = i >> 5, j = i & 31;
        int4 w = src[ss * (NHKV * ND / 4) + j];
        float4 f;
        f.x = (float)w.x; f.y = (float)w.y; f.z = (float)w.z; f.w = (float)w.w;
        *(float4*)&klds[ss][j * 4] = f;
    }
    __syncthreads();
    const float4* qrow = (const float4*)qlds[g];
    const float4* krow = (const float4*)&klds[s][0];
    float acc = 0.f;
#pragma unroll
    for (int j = 0; j < 32; ++j) {
        float4 qa = qrow[j], ka = krow[j];
        acc += qa.x * ka.x + qa.y * ka.y + qa.z * ka.z + qa.w * ka.w;
    }
    float score = acc * kvs[0] * SM_SCALE;
    if (p * NS + s >= len) score = NEGF;
    SC[bhg * (NP * NS) + p * NS + s] = score;
    float m = score;
#pragma unroll
    for (int off = 32; off; off >>= 1) m = fmaxf(m, __shfl_xor(m, off));
    if (s == 0) ST[bhg * NP + p] = m;
}

// one block per (b, hkv, g): top-15 + softmax + current-token term
__global__ __launch_bounds__(256) void select_kernel(const float* __restrict__ v,
                                                     const float* __restrict__ kvs,
                                                     float* __restrict__ ws,
                                                     float* __restrict__ out) {
    const int bhg = blockIdx.x;
    const int b = bhg >> 5;
    const int hkv = (bhg >> 2) & 7;
    const int tid = threadIdx.x;
    const float* SC = ws + WS_SC;
    const float* ST = ws + WS_ST;
    const float* CUR = ws + WS_CUR;
    int* SEL = (int*)(ws + WS_SEL);
    float* PW = ws + WS_PW;
    __shared__ float st[NP];
    __shared__ int sel[KP];
    __shared__ float redm[4], reds[4];
    if (tid < NP) st[tid] = (tid < NP - 1) ? ST[bhg * NP + tid] : NEGF;
    __syncthreads();
    if (tid < 64) {  // wave-parallel selection: 15 rounds of argmax
        for (int r = 0; r < KK; ++r) {
            float v1 = st[tid];
            int i1 = tid;
            float v2 = st[tid + 64];
            int i2 = tid + 64;
            if (v2 > v1) { v1 = v2; i1 = i2; }
#pragma unroll
            for (int off = 32; off; off >>= 1) {
                float ov = __shfl_xor(v1, off);
                int oi = __shfl_xor(i1, off);
                if (ov > v1 || (ov == v1 && oi < i1)) { v1 = ov; i1 = oi; }
            }
            if (tid == 0) sel[r] = i1;
            st[i1] = NEGF;  // all lanes agree on i1
        }
        if (tid == 0) sel[KK] = NP - 1;
    }
    __syncthreads();
    if (tid < KP) {
        out[NB * NH * ND + bhg * KP + tid] = (float)sel[tid];  // indices as f32
        SEL[bhg * KP + tid] = sel[tid];
    }
    // gather selected scores, softmax
    float vals[4];
    float lm = NEGF;
    const float* scb = SC + bhg * (NP * NS);
#pragma unroll
    for (int u = 0; u < 4; ++u) {
        int idx = tid * 4 + u;
        int j = idx >> 6, s2 = idx & 63;
        float sc = scb[sel[j] * NS + s2];
        vals[u] = sc;
        lm = fmaxf(lm, sc);
    }
#pragma unroll
    for (int off = 32; off; off >>= 1) lm = fmaxf(lm, __shfl_xor(lm, off));
    if ((tid & 63) == 0) redm[tid >> 6] = lm;
    __syncthreads();
    const float cur = CUR[bhg];
    float m = fmaxf(fmaxf(redm[0], redm[1]), fmaxf(redm[2], redm[3]));
    m = fmaxf(m, cur);
    float e[4];
    float ls = 0.f;
#pragma unroll
    for (int u = 0; u < 4; ++u) {
        e[u] = expf(vals[u] - m);
        ls += e[u];
    }
#pragma unroll
    for (int off = 32; off; off >>= 1) ls += __shfl_xor(ls, off);
    if ((tid & 63) == 0) reds[tid >> 6] = ls;
    __syncthreads();
    float ecur = expf(cur - m);
    float Z = reds[0] + reds[1] + reds[2] + reds[3] + ecur;
    float inv = 1.0f / Z;
    float pscale = inv * kvs[1];  // fold v-dequant scale into probs
#pragma unroll
    for (int u = 0; u < 4; ++u) PW[bhg * 1024 + tid * 4 + u] = e[u] * pscale;
    if (tid < ND)  // init output with current-token V term (unquantized, no scale)
        out[bhg * ND + tid] = (ecur * inv) * v[(b * NHKV + hkv) * ND + tid];
}

// one block per (b, hkv, g, page-slot): partial PV, atomicAdd into out
__global__ __launch_bounds__(128) void pv_kernel(const int* __restrict__ vc,
                                                 float* __restrict__ ws,
                                                 float* __restrict__ out) {
    const int blk = blockIdx.x;
    const int bhg = blk >> 4;
    const int j = blk & 15;
    const int b = bhg >> 5;
    const int hkv = (bhg >> 2) & 7;
    const int* SEL = (const int*)(ws + WS_SEL);
    const float* PW = ws + WS_PW;
    __shared__ float pl[NS];
    __shared__ float4 red[128];
    const int tid = threadIdx.x;
    if (tid < NS) pl[tid] = PW[bhg * 1024 + j * NS + tid];
    const int page = SEL[bhg * KP + j];
    __syncthreads();
    const int4* vb = (const int4*)(vc + ((b * NP + page) * NS * NHKV + hkv) * ND);
    const int j4 = tid & 31;   // int4 column
    const int s0 = tid >> 5;   // s-stripe 0..3
    float4 acc = {0.f, 0.f, 0.f, 0.f};
#pragma unroll
    for (int s = s0; s < NS; s += 4) {
        int4 w = vb[s * (NHKV * ND / 4) + j4];
        float pv = pl[s];
        acc.x += pv * (float)w.x;
        acc.y += pv * (float)w.y;
        acc.z += pv * (float)w.z;
        acc.w += pv * (float)w.w;
    }
    red[tid] = acc;
    __syncthreads();
    if (tid < 32) {
        float4 a = red[tid], b2 = red[tid + 32], c = red[tid + 64], d2 = red[tid + 96];
        float x = a.x + b2.x + c.x + d2.x;
        float y = a.y + b2.y + c.y + d2.y;
        float z = a.z + b2.z + c.z + d2.z;
        float w = a.w + b2.w + c.w + d2.w;
        float* o = &out[bhg * ND + tid * 4];
        atomicAdd(o + 0, x);
        atomicAdd(o + 1, y);
        atomicAdd(o + 2, z);
        atomicAdd(o + 3, w);
    }
}

extern "C" void kernel_launch(void* const* d_in, const int* in_sizes, int n_in,
                              void* d_out, int out_size, void* d_ws, size_t ws_size,
                              hipStream_t stream) {
    const float* q = (const float*)d_in[0];
    const float* k = (const float*)d_in[1];
    const float* v = (const float*)d_in[2];
    const float* kvs = (const float*)d_in[3];
    const int* kc = (const int*)d_in[4];
    const int* vc = (const int*)d_in[5];
    const int* lens = (const int*)d_in[6];
    const int* tstep = (const int*)d_in[7];
    float* out = (float*)d_out;
    float* ws = (float*)d_ws;

    prep_kernel<<<1, 256, 0, stream>>>(q, k, tstep, ws);
    score_kernel<<<NB * NHKV * NP, 256, 0, stream>>>(kc, kvs, lens, ws);
    select_kernel<<<NB * NHKV * NG, 256, 0, stream>>>(v, kvs, ws, out);
    pv_kernel<<<NB * NHKV * NG * KP, 128, 0, stream>>>(vc, ws, out);
}

// Round 5
// 285.368 us; speedup vs baseline: 1.0752x; 1.0752x over previous
//
#include <hip/hip_runtime.h>

#define NB 4
#define NH 32
#define NHKV 8
#define NG 4
#define ND 128
#define NP 128
#define NS 64
#define KK 15
#define KP 16
#define NEGF -1000000000.0f
#define SM_SCALE 0.088388347648318447f

// workspace layout (float offsets)
#define WS_SC   0                                  // B*Hkv*G*P*S = 1048576
#define WS_ST   (NB*NHKV*NG*NP*NS)                 // B*Hkv*G*P   = 16384
#define WS_SEL  (WS_ST + NB*NHKV*NG*NP)            // B*Hkv*G*KP  = 2048 (int)
#define WS_PW   (WS_SEL + NB*NHKV*NG*KP)           // B*Hkv*G*1024= 131072

// inv_freq MUST match the reference's f32 formulation bit-for-bit:
// 1/powf(10000, j/64). exp2f(-j*log2(10000)/64) perturbs scores ~1e-3 at
// pos=8191 and flips near-tied top-k selections (round-4 failure).
__device__ __forceinline__ float ref_invfreq(int j) {
    return 1.0f / powf(10000.0f, (float)j * (1.0f / 64.0f));
}

// one block per (b, hkv, page); wave g scores query head g for all 64 s.
// q-RoPE fused per block (1 sincosf/thread).
__global__ __launch_bounds__(256) void score_kernel(const float* __restrict__ q,
                                                    const int* __restrict__ kc,
                                                    const float* __restrict__ kvs,
                                                    const int* __restrict__ lens,
                                                    const int* __restrict__ tstep,
                                                    float* __restrict__ ws) {
    // [64][128] linear, float4-column XOR swizzle (c ^ (row&31)):
    // write/read swizzles are the same involution; verified via output-0 pass.
    __shared__ float klds[NS][ND];
    __shared__ float qlds[NG][ND];
    float* SC = ws + WS_SC;
    float* ST = ws + WS_ST;
    const int blk = blockIdx.x;
    const int p = blk & (NP - 1);
    const int bh = blk >> 7;
    const int hkv = bh & (NHKV - 1);
    const int b = bh >> 3;
    const int len = max(lens[b], 1);
    const int tid = threadIdx.x;
    const int g = tid >> 6, s = tid & 63;
    const int bhg = (b * NHKV + hkv) * NG + g;
    if (p * NS >= len) {  // fully masked page (block-uniform): skip K load
        SC[bhg * (NP * NS) + p * NS + s] = NEGF;
        if (s == 0) ST[bhg * NP + p] = NEGF;
        return;
    }
    {   // fused q-RoPE: thread (g, j=s) computes rotated pair j of head g
        const float pos = (float)(tstep[0] - 1);
        const int j = s;
        const float invf = ref_invfreq(j);
        float sn, cs;
        sincosf(pos * invf, &sn, &cs);
        const float* qh = q + (b * NH + hkv * NG + g) * ND;
        float x1 = qh[j], x2 = qh[64 + j];
        qlds[g][j] = x1 * cs - x2 * sn;
        qlds[g][64 + j] = x1 * sn + x2 * cs;
    }
    const int4* src = (const int4*)(kc + ((b * NP + p) * NS * NHKV + hkv) * ND);
    for (int i = tid; i < NS * 32; i += 256) {
        int ss = i >> 5, j = i & 31;
        int4 w = src[ss * (NHKV * ND / 4) + j];
        float4 f;
        f.x = (float)w.x; f.y = (float)w.y; f.z = (float)w.z; f.w = (float)w.w;
        int c = j ^ (ss & 31);                 // swizzled float4 column
        *(float4*)&klds[ss][c * 4] = f;
    }
    __syncthreads();
    const float4* qrow = (const float4*)qlds[g];   // wave-uniform -> broadcast
    const float* kl0 = &klds[0][0];
    // cbase bits: s*128 (bits 7+) | (s&31)<<2 (bits 2-6) are disjoint from
    // jj<<2, so cbase ^ (jj<<2) == row s, swizzled col (jj ^ (s&31)).
    const int cbase = s * ND + ((s & 31) << 2);
    float acc = 0.f;
#pragma unroll
    for (int jj = 0; jj < 32; ++jj) {
        float4 qa = qrow[jj];
        float4 ka = *(const float4*)&kl0[cbase ^ (jj << 2)];
        acc += qa.x * ka.x + qa.y * ka.y + qa.z * ka.z + qa.w * ka.w;
    }
    float score = acc * kvs[0] * SM_SCALE;
    if (p * NS + s >= len) score = NEGF;
    SC[bhg * (NP * NS) + p * NS + s] = score;
    float m = score;
#pragma unroll
    for (int off = 32; off; off >>= 1) m = fmaxf(m, __shfl_xor(m, off));
    if (s == 0) ST[bhg * NP + p] = m;
}

// one block per (b, hkv, g): fused k-RoPE + current-token score, top-15,
// softmax over 1025, P-weights write, output init with current-token V term
__global__ __launch_bounds__(256) void select_kernel(const float* __restrict__ q,
                                                     const float* __restrict__ k,
                                                     const float* __restrict__ v,
                                                     const float* __restrict__ kvs,
                                                     const int* __restrict__ tstep,
                                                     float* __restrict__ ws,
                                                     float* __restrict__ out) {
    const int bhg = blockIdx.x;
    const int b = bhg >> 5;
    const int hkv = (bhg >> 2) & 7;
    const int g = bhg & 3;
    const int tid = threadIdx.x;
    const float* SC = ws + WS_SC;
    const float* ST = ws + WS_ST;
    int* SEL = (int*)(ws + WS_SEL);
    float* PW = ws + WS_PW;
    __shared__ float qh2[ND], kr2[ND], pr[128];
    __shared__ float st[NP];
    __shared__ int sel[KP];
    __shared__ float redm[4], reds[4], curS;
    const float pos = (float)(tstep[0] - 1);
    if (tid < 128) {   // fused RoPE: threads 0-63 rotate q-head, 64-127 k-head
        int j = tid & 63;
        const float invf = ref_invfreq(j);
        float sn, cs;
        sincosf(pos * invf, &sn, &cs);
        if (tid < 64) {
            const float* qh = q + (b * NH + hkv * NG + g) * ND;
            float x1 = qh[j], x2 = qh[64 + j];
            qh2[j] = x1 * cs - x2 * sn;
            qh2[64 + j] = x1 * sn + x2 * cs;
        } else {
            const float* kh = k + (b * NHKV + hkv) * ND;
            float x1 = kh[j], x2 = kh[64 + j];
            kr2[j] = x1 * cs - x2 * sn;
            kr2[64 + j] = x1 * sn + x2 * cs;
        }
    }
    if (tid < NP) st[tid] = (tid < NP - 1) ? ST[bhg * NP + tid] : NEGF;
    __syncthreads();
    if (tid < 128) pr[tid] = qh2[tid] * kr2[tid];
    __syncthreads();
    if (tid < 64) {
        // current-token score: 128-elem dot reduce in one wave
        float val = pr[tid] + pr[tid + 64];
#pragma unroll
        for (int off = 32; off; off >>= 1) val += __shfl_xor(val, off);
        if (tid == 0) curS = val * SM_SCALE;
        // wave-parallel top-15: rounds of argmax (low index wins ties)
        for (int r = 0; r < KK; ++r) {
            float v1 = st[tid];
            int i1 = tid;
            float v2 = st[tid + 64];
            int i2 = tid + 64;
            if (v2 > v1) { v1 = v2; i1 = i2; }
#pragma unroll
            for (int off = 32; off; off >>= 1) {
                float ov = __shfl_xor(v1, off);
                int oi = __shfl_xor(i1, off);
                if (ov > v1 || (ov == v1 && oi < i1)) { v1 = ov; i1 = oi; }
            }
            if (tid == 0) sel[r] = i1;
            st[i1] = NEGF;  // all lanes agree on i1
        }
        if (tid == 0) sel[KK] = NP - 1;
    }
    __syncthreads();
    if (tid < KP) {
        out[NB * NH * ND + bhg * KP + tid] = (float)sel[tid];  // indices as f32
        SEL[bhg * KP + tid] = sel[tid];
    }
    // gather selected scores, softmax over 1024 + current token
    float vals[4];
    float lm = NEGF;
    const float* scb = SC + bhg * (NP * NS);
#pragma unroll
    for (int u = 0; u < 4; ++u) {
        int idx = tid * 4 + u;
        int j = idx >> 6, s2 = idx & 63;
        float sc = scb[sel[j] * NS + s2];
        vals[u] = sc;
        lm = fmaxf(lm, sc);
    }
#pragma unroll
    for (int off = 32; off; off >>= 1) lm = fmaxf(lm, __shfl_xor(lm, off));
    if ((tid & 63) == 0) redm[tid >> 6] = lm;
    __syncthreads();
    const float cur = curS;
    float m = fmaxf(fmaxf(redm[0], redm[1]), fmaxf(redm[2], redm[3]));
    m = fmaxf(m, cur);
    float e[4];
    float ls = 0.f;
#pragma unroll
    for (int u = 0; u < 4; ++u) {
        e[u] = expf(vals[u] - m);
        ls += e[u];
    }
#pragma unroll
    for (int off = 32; off; off >>= 1) ls += __shfl_xor(ls, off);
    if ((tid & 63) == 0) reds[tid >> 6] = ls;
    __syncthreads();
    float ecur = expf(cur - m);
    float Z = reds[0] + reds[1] + reds[2] + reds[3] + ecur;
    float inv = 1.0f / Z;
    float pscale = inv * kvs[1];  // fold v-dequant scale into probs
#pragma unroll
    for (int u = 0; u < 4; ++u) PW[bhg * 1024 + tid * 4 + u] = e[u] * pscale;
    if (tid < ND)  // init output with current-token V term (unquantized)
        out[bhg * ND + tid] = (ecur * inv) * v[(b * NHKV + hkv) * ND + tid];
}

// one block per (b, hkv, g, page-slot): partial PV, atomicAdd into out
__global__ __launch_bounds__(128) void pv_kernel(const int* __restrict__ vc,
                                                 float* __restrict__ ws,
                                                 float* __restrict__ out) {
    const int blk = blockIdx.x;
    const int bhg = blk >> 4;
    const int j = blk & 15;
    const int b = bhg >> 5;
    const int hkv = (bhg >> 2) & 7;
    const int* SEL = (const int*)(ws + WS_SEL);
    const float* PW = ws + WS_PW;
    __shared__ float pl[NS];
    __shared__ float4 red[128];
    const int tid = threadIdx.x;
    if (tid < NS) pl[tid] = PW[bhg * 1024 + j * NS + tid];
    const int page = SEL[bhg * KP + j];
    __syncthreads();
    const int4* vb = (const int4*)(vc + ((b * NP + page) * NS * NHKV + hkv) * ND);
    const int j4 = tid & 31;   // int4 column
    const int s0 = tid >> 5;   // s-stripe 0..3
    float4 acc = {0.f, 0.f, 0.f, 0.f};
#pragma unroll
    for (int s = s0; s < NS; s += 4) {
        int4 w = vb[s * (NHKV * ND / 4) + j4];
        float pv = pl[s];
        acc.x += pv * (float)w.x;
        acc.y += pv * (float)w.y;
        acc.z += pv * (float)w.z;
        acc.w += pv * (float)w.w;
    }
    red[tid] = acc;
    __syncthreads();
    if (tid < 32) {
        float4 a = red[tid], b2 = red[tid + 32], c = red[tid + 64], d2 = red[tid + 96];
        float x = a.x + b2.x + c.x + d2.x;
        float y = a.y + b2.y + c.y + d2.y;
        float z = a.z + b2.z + c.z + d2.z;
        float w = a.w + b2.w + c.w + d2.w;
        float* o = &out[bhg * ND + tid * 4];
        atomicAdd(o + 0, x);
        atomicAdd(o + 1, y);
        atomicAdd(o + 2, z);
        atomicAdd(o + 3, w);
    }
}

extern "C" void kernel_launch(void* const* d_in, const int* in_sizes, int n_in,
                              void* d_out, int out_size, void* d_ws, size_t ws_size,
                              hipStream_t stream) {
    const float* q = (const float*)d_in[0];
    const float* k = (const float*)d_in[1];
    const float* v = (const float*)d_in[2];
    const float* kvs = (const float*)d_in[3];
    const int* kc = (const int*)d_in[4];
    const int* vc = (const int*)d_in[5];
    const int* lens = (const int*)d_in[6];
    const int* tstep = (const int*)d_in[7];
    float* out = (float*)d_out;
    float* ws = (float*)d_ws;

    score_kernel<<<NB * NHKV * NP, 256, 0, stream>>>(q, kc, kvs, lens, tstep, ws);
    select_kernel<<<NB * NHKV * NG, 256, 0, stream>>>(q, k, v, kvs, tstep, ws, out);
    pv_kernel<<<NB * NHKV * NG * KP, 128, 0, stream>>>(vc, ws, out);
}